// Round 7
// baseline (400.925 us; speedup 1.0000x reference)
//
#include <hip/hip_runtime.h>
#include <math.h>

#define B_  4
#define T_  2048
#define DM  1024
#define H_  16
#define DK  64
#define N3  3072

typedef __attribute__((ext_vector_type(8))) __bf16 bf16x8;
typedef __attribute__((ext_vector_type(4))) float f32x4;
typedef __attribute__((ext_vector_type(4))) unsigned int u32x4;

static __device__ __forceinline__ unsigned int f2bf(float f) {
    union { float f; unsigned int u; } v; v.f = f;
    return (v.u + 0x7fffu + ((v.u >> 16) & 1u)) >> 16;   // RNE
}
static __device__ __forceinline__ unsigned int pack2bf(float a, float b) {
    return f2bf(a) | (f2bf(b) << 16);
}

// ---------------- prep: fp32 -> bf16 straight copy (x) ----------------
__global__ __launch_bounds__(256)
void convert_copy(const float* __restrict__ src, unsigned short* __restrict__ dst, int n8)
{
    const int i = blockIdx.x * 256 + threadIdx.x;
    if (i >= n8) return;
    const float4 f0 = ((const float4*)src)[i * 2];
    const float4 f1 = ((const float4*)src)[i * 2 + 1];
    u32x4 wv;
    wv.x = pack2bf(f0.x, f0.y); wv.y = pack2bf(f0.z, f0.w);
    wv.z = pack2bf(f1.x, f1.y); wv.w = pack2bf(f1.z, f1.w);
    ((u32x4*)dst)[i] = wv;
}

// ---------------- prep: fp32 [K][N] -> bf16 transposed [N][K] ----------------
__global__ __launch_bounds__(256)
void convert_T(const float* __restrict__ src, unsigned short* __restrict__ dst, int K, int N)
{
    __shared__ float tile[32][33];
    const int n0 = blockIdx.x * 32, k0 = blockIdx.y * 32;
    const int tid = threadIdx.x;
    #pragma unroll
    for (int p = 0; p < 4; ++p) {
        const int idx = p * 256 + tid;
        const int r = idx >> 5, c = idx & 31;
        tile[r][c] = src[(size_t)(k0 + r) * N + n0 + c];
    }
    __syncthreads();
    #pragma unroll
    for (int p = 0; p < 4; ++p) {
        const int idx = p * 256 + tid;
        const int r = idx >> 5, c = idx & 31;
        dst[(size_t)(n0 + r) * K + k0 + c] = (unsigned short)f2bf(tile[c][r]);
    }
}

// ============ Kernel 1: QKV GEMM (bf16 MFMA) + RoPE ============
// Q pre-scaled by 0.125*log2(e) (softmax uses exp2). Writes Q,K [b][h][t][d], V as Vt [b][h][d][t].
__global__ __launch_bounds__(256)
void qkv_rope_kernel(const unsigned short* __restrict__ xb,     // [8192][1024] bf16
                     const unsigned short* __restrict__ WT,     // [3072][1024] bf16 (Wqkv^T)
                     const int* __restrict__ pos,
                     unsigned short* __restrict__ Qb,
                     unsigned short* __restrict__ Kb,
                     unsigned short* __restrict__ Vtb)
{
    __shared__ u32x4 Asv[512];   // [kb 4][row 128]
    __shared__ u32x4 Bsv[512];
    const int tid  = threadIdx.x;
    const int col0 = blockIdx.x * 128;   // 24 tiles over N=3072
    const int row0 = blockIdx.y * 128;   // 64 tiles over M=8192
    const int l = tid & 63, w = tid >> 6;
    const int wr = w >> 1, wc = w & 1;
    const int lr = l & 15, hi4 = l >> 4;

    f32x4 acc[4][4];
    #pragma unroll
    for (int m = 0; m < 4; ++m)
        #pragma unroll
        for (int n = 0; n < 4; ++n)
            acc[m][n] = (f32x4){0.f, 0.f, 0.f, 0.f};

    for (int k0 = 0; k0 < DM; k0 += 32) {
        __syncthreads();
        #pragma unroll
        for (int pass = 0; pass < 2; ++pass) {
            const int c = pass * 256 + tid;
            const int row = c >> 2, kb = c & 3;
            Asv[kb * 128 + row] = *(const u32x4*)&xb[(size_t)(row0 + row) * DM + k0 + kb * 8];
            Bsv[kb * 128 + row] = *(const u32x4*)&WT[(size_t)(col0 + row) * DM + k0 + kb * 8];
        }
        __syncthreads();
        u32x4 a[4], b[4];
        #pragma unroll
        for (int m = 0; m < 4; ++m) a[m] = Asv[hi4 * 128 + wr * 64 + m * 16 + lr];
        #pragma unroll
        for (int n = 0; n < 4; ++n) b[n] = Bsv[hi4 * 128 + wc * 64 + n * 16 + lr];
        #pragma unroll
        for (int m = 0; m < 4; ++m)
            #pragma unroll
            for (int n = 0; n < 4; ++n)
                acc[m][n] = __builtin_amdgcn_mfma_f32_16x16x32_bf16(
                    __builtin_bit_cast(bf16x8, a[m]),
                    __builtin_bit_cast(bf16x8, b[n]),
                    acc[m][n], 0, 0, 0);
    }

    const int which = col0 >> 10;                      // 0=q 1=k 2=v (tile never crosses)
    const int h     = ((col0 & 1023) >> 6) + wc;
    const int bb    = row0 >> 11;
    const int t0w   = (row0 & 2047) + wr * 64;

    if (which == 2) {
        // V: lane holds t-run of 4 for fixed d -> free transpose, write Vt[d][t]
        #pragma unroll
        for (int n = 0; n < 4; ++n) {
            const int d = n * 16 + lr;
            #pragma unroll
            for (int m = 0; m < 4; ++m) {
                uint2 val;
                val.x = pack2bf(acc[m][n][0], acc[m][n][1]);
                val.y = pack2bf(acc[m][n][2], acc[m][n][3]);
                *(uint2*)&Vtb[((size_t)(bb * H_ + h) * DK + d) * T_ + t0w + m * 16 + hi4 * 4] = val;
            }
        }
    } else {
        unsigned short* dst = (which == 0) ? Qb : Kb;
        // fold 1/sqrt(dk) * log2(e) into Q so attention softmax can use exp2
        const float postscale = (which == 0) ? 0.18033688f : 1.0f;
        #pragma unroll
        for (int n = 0; n < 4; ++n) {
            const int d = n * 16 + lr;
            const float ifr = __powf(10000.0f, -(float)(d & ~1) * (1.0f / 64.0f));
            #pragma unroll
            for (int m = 0; m < 4; ++m)
                #pragma unroll
                for (int r = 0; r < 4; ++r) {
                    const int t = t0w + m * 16 + hi4 * 4 + r;
                    const float v = acc[m][n][r];
                    const float partner = __shfl_xor(v, 1, 64);   // pair (d^1)
                    float s, c;
                    __sincosf((float)pos[t] * ifr, &s, &c);
                    const float rv = ((d & 1) ? (partner * s + v * c) : (v * c - partner * s)) * postscale;
                    dst[((size_t)(bb * H_ + h) * T_ + t) * DK + d] = (unsigned short)f2bf(rv);
                }
        }
    }
}

// ============ Kernel 2: causal flash attention, swapped-operand, pipelined K/V ============
// Block: 4 waves, Q-tile 128 (32 q/wave), KV-tile 64, double-buffered LDS staging:
// issue global loads for tile t+1 into regs, compute tile t, barrier, regs->LDS, barrier.
__global__ __launch_bounds__(256)
void flash_attn_kernel(const unsigned short* __restrict__ Qg,
                       const unsigned short* __restrict__ Kg,
                       const unsigned short* __restrict__ Vtg,
                       unsigned short* __restrict__ Og)
{
    __shared__ u32x4 K4[2][512];           // [buf][kv 64 * chunk 8], chunk ^= kv&7
    __shared__ u32x4 Vt4[2][512];          // [buf][d 64 * chunk 8],  chunk ^= d&7
    __shared__ unsigned int Pex[4][16 * 36];  // per-wave [q 16][word], stride 36

    const int tid = threadIdx.x;
    const int l = tid & 63, w = tid >> 6;
    const int lr = l & 15, hi4 = l >> 4;
    const int qt = gridDim.x - 1 - blockIdx.x;   // longest blocks first (causal skew)
    const int h = blockIdx.y, b = blockIdx.z;
    const int q0 = qt * 128;
    const size_t hb = (size_t)(b * H_ + h) * T_ * DK;
    unsigned int* pw = &Pex[w][0];

    // staging coords: thread handles chunks c = tid and 256+tid of each 512-chunk tile
    int srow[2], scc[2], sdst[2];
    #pragma unroll
    for (int p = 0; p < 2; ++p) {
        const int c = p * 256 + tid;
        srow[p] = c >> 3; scc[p] = c & 7;
        sdst[p] = srow[p] * 8 + (scc[p] ^ (srow[p] & 7));
    }

    // Q fragments (B-operand: col=lr -> q-row, k=d=ks*32+hi4*8+j)
    u32x4 qf[2][2];
    #pragma unroll
    for (int m = 0; m < 2; ++m)
        #pragma unroll
        for (int ks = 0; ks < 2; ++ks)
            qf[m][ks] = *(const u32x4*)&Qg[hb + (size_t)(q0 + w * 32 + m * 16 + lr) * DK
                                           + ks * 32 + hi4 * 8];

    f32x4 acc_ot[2][4];                    // [m][df]: O^T frag, col=q(lr), row=d
    float m_i[2], l_i[2];
    #pragma unroll
    for (int m = 0; m < 2; ++m) {
        m_i[m] = -INFINITY; l_i[m] = 0.f;
        #pragma unroll
        for (int df = 0; df < 4; ++df) acc_ot[m][df] = (f32x4){0.f, 0.f, 0.f, 0.f};
    }

    const int qwave = q0 + w * 32;
    const int nkt = (q0 >> 6) + 2;

    // prologue: stage tile 0 into buf 0
    u32x4 kr[2], vr[2];
    #pragma unroll
    for (int p = 0; p < 2; ++p) {
        kr[p] = *(const u32x4*)&Kg [hb + (size_t)srow[p] * DK + scc[p] * 8];
        vr[p] = *(const u32x4*)&Vtg[hb + (size_t)srow[p] * T_ + scc[p] * 8];
    }
    #pragma unroll
    for (int p = 0; p < 2; ++p) { K4[0][sdst[p]] = kr[p]; Vt4[0][sdst[p]] = vr[p]; }
    __syncthreads();

    int cur = 0;
    for (int kt = 0; kt < nkt; ++kt) {
        const int kv0 = kt * 64;
        const bool havenext = (kt + 1 < nkt);
        if (havenext) {
            const int kvn = kv0 + 64;
            #pragma unroll
            for (int p = 0; p < 2; ++p) {
                kr[p] = *(const u32x4*)&Kg [hb + (size_t)(kvn + srow[p]) * DK + scc[p] * 8];
                vr[p] = *(const u32x4*)&Vtg[hb + (size_t)srow[p] * T_ + kvn + scc[p] * 8];
            }
        }

        if (kv0 <= qwave + 31) {   // wave-uniform: skip fully-masked tiles
            const u32x4* Kc  = &K4[cur][0];
            const u32x4* Vtc = &Vt4[cur][0];

            // ---- S^T = mfma(K, Q): D col=q(lr), row=kv(nf*16+hi4*4+r) ----
            f32x4 st[2][4];
            #pragma unroll
            for (int m = 0; m < 2; ++m)
                #pragma unroll
                for (int nf = 0; nf < 4; ++nf)
                    st[m][nf] = (f32x4){0.f, 0.f, 0.f, 0.f};
            __builtin_amdgcn_s_setprio(1);
            #pragma unroll
            for (int ks = 0; ks < 2; ++ks) {
                u32x4 kb4[4];
                #pragma unroll
                for (int nf = 0; nf < 4; ++nf) {
                    const int row = nf * 16 + lr;
                    kb4[nf] = Kc[row * 8 + ((ks * 4 + hi4) ^ (row & 7))];
                }
                #pragma unroll
                for (int m = 0; m < 2; ++m)
                    #pragma unroll
                    for (int nf = 0; nf < 4; ++nf)
                        st[m][nf] = __builtin_amdgcn_mfma_f32_16x16x32_bf16(
                            __builtin_bit_cast(bf16x8, kb4[nf]),
                            __builtin_bit_cast(bf16x8, qf[m][ks]), st[m][nf], 0, 0, 0);
            }
            __builtin_amdgcn_s_setprio(0);

            const bool needmask = (kv0 + 63 > qwave);
            u32x4 pfrag[2][2];
            #pragma unroll
            for (int m = 0; m < 2; ++m) {
                const int qg = qwave + m * 16 + lr;
                float sv[4][4];
                #pragma unroll
                for (int nf = 0; nf < 4; ++nf)
                    #pragma unroll
                    for (int r = 0; r < 4; ++r) sv[nf][r] = st[m][nf][r];
                if (needmask) {   // wave-uniform branch
                    #pragma unroll
                    for (int nf = 0; nf < 4; ++nf)
                        #pragma unroll
                        for (int r = 0; r < 4; ++r)
                            if ((kv0 + nf * 16 + hi4 * 4 + r) > qg) sv[nf][r] = -INFINITY;
                }
                float mx = sv[0][0];
                #pragma unroll
                for (int nf = 0; nf < 4; ++nf)
                    #pragma unroll
                    for (int r = 0; r < 4; ++r) mx = fmaxf(mx, sv[nf][r]);
                mx = fmaxf(mx, __shfl_xor(mx, 16, 64));
                mx = fmaxf(mx, __shfl_xor(mx, 32, 64));
                const float mnew = fmaxf(m_i[m], mx);
                const float alpha = exp2f(m_i[m] - mnew);
                m_i[m] = mnew;
                float p[4][4], rs = 0.f;
                #pragma unroll
                for (int nf = 0; nf < 4; ++nf)
                    #pragma unroll
                    for (int r = 0; r < 4; ++r) {
                        p[nf][r] = exp2f(sv[nf][r] - mnew);
                        rs += p[nf][r];
                    }
                rs += __shfl_xor(rs, 16, 64);
                rs += __shfl_xor(rs, 32, 64);
                l_i[m] = l_i[m] * alpha + rs;
                #pragma unroll
                for (int df = 0; df < 4; ++df) acc_ot[m][df] *= alpha;
                // pack P row -> per-wave LDS exchange [q=lr][word=kv/2], stride 36
                #pragma unroll
                for (int nf = 0; nf < 4; ++nf) {
                    uint2 pr;
                    pr.x = pack2bf(p[nf][0], p[nf][1]);
                    pr.y = pack2bf(p[nf][2], p[nf][3]);
                    *(uint2*)&pw[lr * 36 + nf * 8 + hi4 * 2] = pr;
                }
                #pragma unroll
                for (int ks = 0; ks < 2; ++ks)
                    pfrag[m][ks] = *(const u32x4*)&pw[lr * 36 + ks * 16 + hi4 * 4];
            }

            // ---- O^T += mfma(Vt, P): col=q(lr), row=d ----
            __builtin_amdgcn_s_setprio(1);
            #pragma unroll
            for (int ks = 0; ks < 2; ++ks) {
                u32x4 vb[4];
                #pragma unroll
                for (int df = 0; df < 4; ++df) {
                    const int d = df * 16 + lr;
                    vb[df] = Vtc[d * 8 + ((ks * 4 + hi4) ^ (d & 7))];
                }
                #pragma unroll
                for (int m = 0; m < 2; ++m)
                    #pragma unroll
                    for (int df = 0; df < 4; ++df)
                        acc_ot[m][df] = __builtin_amdgcn_mfma_f32_16x16x32_bf16(
                            __builtin_bit_cast(bf16x8, vb[df]),
                            __builtin_bit_cast(bf16x8, pfrag[m][ks]), acc_ot[m][df], 0, 0, 0);
            }
            __builtin_amdgcn_s_setprio(0);
        }

        __syncthreads();    // all reads of LDS done (this iter) before overwrite of other buf
        if (havenext) {
            #pragma unroll
            for (int p = 0; p < 2; ++p) {
                K4[cur ^ 1][sdst[p]] = kr[p];
                Vt4[cur ^ 1][sdst[p]] = vr[p];
            }
        }
        __syncthreads();    // staged data visible before next iter reads it
        cur ^= 1;
    }

    // ---- epilogue: O^T -> O via per-wave LDS, then coalesced bf16 stores ----
    #pragma unroll
    for (int m = 0; m < 2; ++m) {
        const float inv = 1.0f / l_i[m];
        #pragma unroll
        for (int df = 0; df < 4; ++df) {
            uint2 pr;
            pr.x = pack2bf(acc_ot[m][df][0] * inv, acc_ot[m][df][1] * inv);
            pr.y = pack2bf(acc_ot[m][df][2] * inv, acc_ot[m][df][3] * inv);
            *(uint2*)&pw[lr * 36 + df * 8 + hi4 * 2] = pr;
        }
        #pragma unroll
        for (int ks2 = 0; ks2 < 2; ++ks2) {
            const u32x4 ov = *(const u32x4*)&pw[lr * 36 + ks2 * 16 + hi4 * 4];
            *(u32x4*)&Og[hb + (size_t)(qwave + m * 16 + lr) * DK + ks2 * 32 + hi4 * 8] = ov;
        }
    }
}

// ============ Kernel 3: output projection (bf16 MFMA) ============
__global__ __launch_bounds__(256)
void out_proj_kernel(const unsigned short* __restrict__ Ob,   // [b][h][t][d] bf16
                     const unsigned short* __restrict__ WoT,  // [1024][1024] bf16 (Wo^T)
                     float* __restrict__ out)
{
    __shared__ u32x4 Asv[512];
    __shared__ u32x4 Bsv[512];
    const int tid  = threadIdx.x;
    const int col0 = blockIdx.x * 128;
    const int row0 = blockIdx.y * 128;
    const int l = tid & 63, w = tid >> 6;
    const int wr = w >> 1, wc = w & 1;
    const int lr = l & 15, hi4 = l >> 4;
    const int bb = row0 >> 11, trow0 = row0 & 2047;

    f32x4 acc[4][4];
    #pragma unroll
    for (int m = 0; m < 4; ++m)
        #pragma unroll
        for (int n = 0; n < 4; ++n)
            acc[m][n] = (f32x4){0.f, 0.f, 0.f, 0.f};

    for (int k0 = 0; k0 < DM; k0 += 32) {
        __syncthreads();
        #pragma unroll
        for (int pass = 0; pass < 2; ++pass) {
            const int c = pass * 256 + tid;
            const int row = c >> 2, kb = c & 3;
            const int k = k0 + kb * 8;
            const int hh = k >> 6, dd = k & 63;
            Asv[kb * 128 + row] =
                *(const u32x4*)&Ob[((size_t)(bb * H_ + hh) * T_ + trow0 + row) * DK + dd];
            Bsv[kb * 128 + row] =
                *(const u32x4*)&WoT[(size_t)(col0 + row) * DM + k0 + kb * 8];
        }
        __syncthreads();
        u32x4 a[4], b[4];
        #pragma unroll
        for (int m = 0; m < 4; ++m) a[m] = Asv[hi4 * 128 + wr * 64 + m * 16 + lr];
        #pragma unroll
        for (int n = 0; n < 4; ++n) b[n] = Bsv[hi4 * 128 + wc * 64 + n * 16 + lr];
        #pragma unroll
        for (int m = 0; m < 4; ++m)
            #pragma unroll
            for (int n = 0; n < 4; ++n)
                acc[m][n] = __builtin_amdgcn_mfma_f32_16x16x32_bf16(
                    __builtin_bit_cast(bf16x8, a[m]),
                    __builtin_bit_cast(bf16x8, b[n]),
                    acc[m][n], 0, 0, 0);
    }

    #pragma unroll
    for (int n = 0; n < 4; ++n) {
        const int gc = col0 + wc * 64 + n * 16 + lr;
        #pragma unroll
        for (int m = 0; m < 4; ++m)
            #pragma unroll
            for (int r = 0; r < 4; ++r)
                out[(size_t)(row0 + wr * 64 + m * 16 + hi4 * 4 + r) * DM + gc] = acc[m][n][r];
    }
}

extern "C" void kernel_launch(void* const* d_in, const int* in_sizes, int n_in,
                              void* d_out, int out_size, void* d_ws, size_t ws_size,
                              hipStream_t stream)
{
    const float* x    = (const float*)d_in[0];
    const float* Wqkv = (const float*)d_in[1];
    const float* Wo   = (const float*)d_in[2];
    const int*   pos  = (const int*)d_in[3];
    float* out = (float*)d_out;

    unsigned short* ws    = (unsigned short*)d_ws;
    unsigned short* xb    = ws;                      // 8388608
    unsigned short* WqkvT = xb    + 8388608;         // 3145728
    unsigned short* WoT   = WqkvT + 3145728;         // 1048576
    unsigned short* Qb    = WoT   + 1048576;         // 8388608
    unsigned short* Kb    = Qb    + 8388608;         // 8388608
    unsigned short* Vtb   = Kb    + 8388608;         // 8388608  ([b][h][d][t])
    unsigned short* Ob    = Vtb   + 8388608;         // 8388608

    convert_copy<<<dim3(4096), 256, 0, stream>>>(x, xb, 1048576);
    convert_T<<<dim3(96, 32), 256, 0, stream>>>(Wqkv, WqkvT, 1024, 3072);
    convert_T<<<dim3(32, 32), 256, 0, stream>>>(Wo, WoT, 1024, 1024);
    qkv_rope_kernel<<<dim3(24, 64), 256, 0, stream>>>(xb, WqkvT, pos, Qb, Kb, Vtb);
    flash_attn_kernel<<<dim3(16, 16, 4), 256, 0, stream>>>(Qb, Kb, Vtb, Ob);
    out_proj_kernel<<<dim3(8, 64), 256, 0, stream>>>(Ob, WoT, out);
}

// Round 8
// 314.611 us; speedup vs baseline: 1.2744x; 1.2744x over previous
//
#include <hip/hip_runtime.h>
#include <math.h>

#define B_  4
#define T_  2048
#define DM  1024
#define H_  16
#define DK  64
#define N3  3072

typedef __attribute__((ext_vector_type(8))) __bf16 bf16x8;
typedef __attribute__((ext_vector_type(4))) float f32x4;
typedef __attribute__((ext_vector_type(4))) unsigned int u32x4;

static __device__ __forceinline__ unsigned int f2bf(float f) {
    union { float f; unsigned int u; } v; v.f = f;
    return (v.u + 0x7fffu + ((v.u >> 16) & 1u)) >> 16;   // RNE
}
static __device__ __forceinline__ unsigned int pack2bf(float a, float b) {
    return f2bf(a) | (f2bf(b) << 16);
}

// ---------------- prep: fp32 -> bf16 straight copy (x) ----------------
__global__ __launch_bounds__(256)
void convert_copy(const float* __restrict__ src, unsigned short* __restrict__ dst, int n8)
{
    const int i = blockIdx.x * 256 + threadIdx.x;
    if (i >= n8) return;
    const float4 f0 = ((const float4*)src)[i * 2];
    const float4 f1 = ((const float4*)src)[i * 2 + 1];
    u32x4 wv;
    wv.x = pack2bf(f0.x, f0.y); wv.y = pack2bf(f0.z, f0.w);
    wv.z = pack2bf(f1.x, f1.y); wv.w = pack2bf(f1.z, f1.w);
    ((u32x4*)dst)[i] = wv;
}

// ---------------- prep: fp32 [K][N] -> bf16 transposed [N][K] ----------------
__global__ __launch_bounds__(256)
void convert_T(const float* __restrict__ src, unsigned short* __restrict__ dst, int K, int N)
{
    __shared__ float tile[32][33];
    const int n0 = blockIdx.x * 32, k0 = blockIdx.y * 32;
    const int tid = threadIdx.x;
    #pragma unroll
    for (int p = 0; p < 4; ++p) {
        const int idx = p * 256 + tid;
        const int r = idx >> 5, c = idx & 31;
        tile[r][c] = src[(size_t)(k0 + r) * N + n0 + c];
    }
    __syncthreads();
    #pragma unroll
    for (int p = 0; p < 4; ++p) {
        const int idx = p * 256 + tid;
        const int r = idx >> 5, c = idx & 31;
        dst[(size_t)(n0 + r) * K + k0 + c] = (unsigned short)f2bf(tile[c][r]);
    }
}

// ============ Kernel 1: QKV GEMM (bf16 MFMA) + RoPE ============
// Q pre-scaled by 1/8. Writes Q,K as [b][h][t][d], V as Vt [b][h][d][t].
__global__ __launch_bounds__(256)
void qkv_rope_kernel(const unsigned short* __restrict__ xb,     // [8192][1024] bf16
                     const unsigned short* __restrict__ WT,     // [3072][1024] bf16 (Wqkv^T)
                     const int* __restrict__ pos,
                     unsigned short* __restrict__ Qb,
                     unsigned short* __restrict__ Kb,
                     unsigned short* __restrict__ Vtb)
{
    __shared__ u32x4 Asv[512];   // [kb 4][row 128]
    __shared__ u32x4 Bsv[512];
    const int tid  = threadIdx.x;
    const int col0 = blockIdx.x * 128;   // 24 tiles over N=3072
    const int row0 = blockIdx.y * 128;   // 64 tiles over M=8192
    const int l = tid & 63, w = tid >> 6;
    const int wr = w >> 1, wc = w & 1;
    const int lr = l & 15, hi4 = l >> 4;

    f32x4 acc[4][4];
    #pragma unroll
    for (int m = 0; m < 4; ++m)
        #pragma unroll
        for (int n = 0; n < 4; ++n)
            acc[m][n] = (f32x4){0.f, 0.f, 0.f, 0.f};

    for (int k0 = 0; k0 < DM; k0 += 32) {
        __syncthreads();
        #pragma unroll
        for (int pass = 0; pass < 2; ++pass) {
            const int c = pass * 256 + tid;
            const int row = c >> 2, kb = c & 3;
            Asv[kb * 128 + row] = *(const u32x4*)&xb[(size_t)(row0 + row) * DM + k0 + kb * 8];
            Bsv[kb * 128 + row] = *(const u32x4*)&WT[(size_t)(col0 + row) * DM + k0 + kb * 8];
        }
        __syncthreads();
        u32x4 a[4], b[4];
        #pragma unroll
        for (int m = 0; m < 4; ++m) a[m] = Asv[hi4 * 128 + wr * 64 + m * 16 + lr];
        #pragma unroll
        for (int n = 0; n < 4; ++n) b[n] = Bsv[hi4 * 128 + wc * 64 + n * 16 + lr];
        #pragma unroll
        for (int m = 0; m < 4; ++m)
            #pragma unroll
            for (int n = 0; n < 4; ++n)
                acc[m][n] = __builtin_amdgcn_mfma_f32_16x16x32_bf16(
                    __builtin_bit_cast(bf16x8, a[m]),
                    __builtin_bit_cast(bf16x8, b[n]),
                    acc[m][n], 0, 0, 0);
    }

    const int which = col0 >> 10;                      // 0=q 1=k 2=v (tile never crosses)
    const int h     = ((col0 & 1023) >> 6) + wc;
    const int bb    = row0 >> 11;
    const int t0w   = (row0 & 2047) + wr * 64;

    if (which == 2) {
        // V: lane holds t-run of 4 for fixed d -> free transpose, write Vt[d][t]
        #pragma unroll
        for (int n = 0; n < 4; ++n) {
            const int d = n * 16 + lr;
            #pragma unroll
            for (int m = 0; m < 4; ++m) {
                uint2 val;
                val.x = pack2bf(acc[m][n][0], acc[m][n][1]);
                val.y = pack2bf(acc[m][n][2], acc[m][n][3]);
                *(uint2*)&Vtb[((size_t)(bb * H_ + h) * DK + d) * T_ + t0w + m * 16 + hi4 * 4] = val;
            }
        }
    } else {
        unsigned short* dst = (which == 0) ? Qb : Kb;
        const float postscale = (which == 0) ? 0.125f : 1.0f;   // fold 1/sqrt(dk) into Q
        #pragma unroll
        for (int n = 0; n < 4; ++n) {
            const int d = n * 16 + lr;
            const float ifr = __powf(10000.0f, -(float)(d & ~1) * (1.0f / 64.0f));
            #pragma unroll
            for (int m = 0; m < 4; ++m)
                #pragma unroll
                for (int r = 0; r < 4; ++r) {
                    const int t = t0w + m * 16 + hi4 * 4 + r;
                    const float v = acc[m][n][r];
                    const float partner = __shfl_xor(v, 1, 64);   // pair (d^1)
                    float s, c;
                    __sincosf((float)pos[t] * ifr, &s, &c);
                    const float rv = ((d & 1) ? (partner * s + v * c) : (v * c - partner * s)) * postscale;
                    dst[((size_t)(bb * H_ + h) * T_ + t) * DK + d] = (unsigned short)f2bf(rv);
                }
        }
    }
}

// ============ Kernel 2: causal flash attention, swapped-operand bf16 MFMA ============
// Round-6 structure (single-buffered staging) + XCD-aware 1D block swizzle:
// lin = qt*64 + (b*16+h)  =>  lin % 8 == headgroup % 8, so all 16 q-blocks of one
// head land on ONE XCD and its L2 holds that head's K/V (8 groups x 512KB = 4MB).
__global__ __launch_bounds__(256)
void flash_attn_kernel(const unsigned short* __restrict__ Qg,
                       const unsigned short* __restrict__ Kg,
                       const unsigned short* __restrict__ Vtg,
                       unsigned short* __restrict__ Og)
{
    __shared__ u32x4 K4[512];              // [kv 64][chunk 8], chunk ^= kv&7
    __shared__ u32x4 Vt4[512];             // [d 64][chunk 8],  chunk ^= d&7
    __shared__ unsigned int Pex[4][16 * 36];  // per-wave [q 16][word], stride 36

    const int tid = threadIdx.x;
    const int l = tid & 63, w = tid >> 6;
    const int lr = l & 15, hi4 = l >> 4;
    const int lin = blockIdx.x;            // 1024 blocks
    const int qt  = 15 - (lin >> 6);       // longest q-tiles first
    const int g   = lin & 63;              // headgroup: same g -> same XCD (g%8)
    const int h   = g & 15, b = g >> 4;
    const int q0 = qt * 128;
    const size_t hb = (size_t)(b * H_ + h) * T_ * DK;
    unsigned int* pw = &Pex[w][0];

    // Q fragments (B-operand: col=lr -> q-row, k=d=ks*32+hi4*8+j)
    u32x4 qf[2][2];
    #pragma unroll
    for (int m = 0; m < 2; ++m)
        #pragma unroll
        for (int ks = 0; ks < 2; ++ks)
            qf[m][ks] = *(const u32x4*)&Qg[hb + (size_t)(q0 + w * 32 + m * 16 + lr) * DK
                                           + ks * 32 + hi4 * 8];

    f32x4 acc_ot[2][4];                    // [m][df]: O^T frag, col=q(lr), row=d
    float m_i[2], l_i[2];
    #pragma unroll
    for (int m = 0; m < 2; ++m) {
        m_i[m] = -INFINITY; l_i[m] = 0.f;
        #pragma unroll
        for (int df = 0; df < 4; ++df) acc_ot[m][df] = (f32x4){0.f, 0.f, 0.f, 0.f};
    }

    const int qwave = q0 + w * 32;
    const int nkt = (q0 >> 6) + 2;
    for (int kt = 0; kt < nkt; ++kt) {
        const int kv0 = kt * 64;
        __syncthreads();
        #pragma unroll
        for (int pass = 0; pass < 2; ++pass) {
            const int c = pass * 256 + tid;
            const int row = c >> 3, cc = c & 7;
            K4 [row * 8 + (cc ^ (row & 7))] = *(const u32x4*)&Kg [hb + (size_t)(kv0 + row) * DK + cc * 8];
            Vt4[row * 8 + (cc ^ (row & 7))] = *(const u32x4*)&Vtg[hb + (size_t)row * T_ + kv0 + cc * 8];
        }
        __syncthreads();
        if (kv0 > qwave + 31) continue;    // wave-uniform: fully masked

        // ---- S^T = mfma(K, Q): D col=q(lr), row=kv(nf*16+hi4*4+r) ----
        f32x4 st[2][4];
        #pragma unroll
        for (int m = 0; m < 2; ++m)
            #pragma unroll
            for (int nf = 0; nf < 4; ++nf)
                st[m][nf] = (f32x4){0.f, 0.f, 0.f, 0.f};
        #pragma unroll
        for (int ks = 0; ks < 2; ++ks) {
            u32x4 kb4[4];
            #pragma unroll
            for (int nf = 0; nf < 4; ++nf) {
                const int row = nf * 16 + lr;
                kb4[nf] = K4[row * 8 + ((ks * 4 + hi4) ^ (row & 7))];
            }
            #pragma unroll
            for (int m = 0; m < 2; ++m)
                #pragma unroll
                for (int nf = 0; nf < 4; ++nf)
                    st[m][nf] = __builtin_amdgcn_mfma_f32_16x16x32_bf16(
                        __builtin_bit_cast(bf16x8, kb4[nf]),
                        __builtin_bit_cast(bf16x8, qf[m][ks]), st[m][nf], 0, 0, 0);
        }

        const bool needmask = (kv0 + 63 > qwave);
        u32x4 pfrag[2][2];
        #pragma unroll
        for (int m = 0; m < 2; ++m) {
            const int qg = qwave + m * 16 + lr;
            float sv[4][4];
            #pragma unroll
            for (int nf = 0; nf < 4; ++nf)
                #pragma unroll
                for (int r = 0; r < 4; ++r) {
                    float xv = st[m][nf][r];
                    if (needmask && (kv0 + nf * 16 + hi4 * 4 + r) > qg) xv = -INFINITY;
                    sv[nf][r] = xv;
                }
            // row max: 15 local + 2 shuffles (over hi4 groups)
            float mx = sv[0][0];
            #pragma unroll
            for (int nf = 0; nf < 4; ++nf)
                #pragma unroll
                for (int r = 0; r < 4; ++r) mx = fmaxf(mx, sv[nf][r]);
            mx = fmaxf(mx, __shfl_xor(mx, 16, 64));
            mx = fmaxf(mx, __shfl_xor(mx, 32, 64));
            const float mnew = fmaxf(m_i[m], mx);
            const float alpha = __expf(m_i[m] - mnew);
            m_i[m] = mnew;
            float p[4][4], rs = 0.f;
            #pragma unroll
            for (int nf = 0; nf < 4; ++nf)
                #pragma unroll
                for (int r = 0; r < 4; ++r) {
                    p[nf][r] = __expf(sv[nf][r] - mnew);
                    rs += p[nf][r];
                }
            rs += __shfl_xor(rs, 16, 64);
            rs += __shfl_xor(rs, 32, 64);
            l_i[m] = l_i[m] * alpha + rs;
            #pragma unroll
            for (int df = 0; df < 4; ++df) acc_ot[m][df] *= alpha;
            // pack P row -> per-wave LDS exchange [q=lr][word=kv/2], stride 36
            #pragma unroll
            for (int nf = 0; nf < 4; ++nf) {
                uint2 pr;
                pr.x = pack2bf(p[nf][0], p[nf][1]);
                pr.y = pack2bf(p[nf][2], p[nf][3]);
                *(uint2*)&pw[lr * 36 + nf * 8 + hi4 * 2] = pr;
            }
            // read back as B-frag: col=q(lr), k = kv = ks*32 + hi4*8 + j
            #pragma unroll
            for (int ks = 0; ks < 2; ++ks)
                pfrag[m][ks] = *(const u32x4*)&pw[lr * 36 + ks * 16 + hi4 * 4];
        }

        // ---- O^T += mfma(Vt, P): col=q(lr), row=d ----
        #pragma unroll
        for (int ks = 0; ks < 2; ++ks) {
            u32x4 vb[4];
            #pragma unroll
            for (int df = 0; df < 4; ++df) {
                const int d = df * 16 + lr;
                vb[df] = Vt4[d * 8 + ((ks * 4 + hi4) ^ (d & 7))];
            }
            #pragma unroll
            for (int m = 0; m < 2; ++m)
                #pragma unroll
                for (int df = 0; df < 4; ++df)
                    acc_ot[m][df] = __builtin_amdgcn_mfma_f32_16x16x32_bf16(
                        __builtin_bit_cast(bf16x8, vb[df]),
                        __builtin_bit_cast(bf16x8, pfrag[m][ks]), acc_ot[m][df], 0, 0, 0);
        }
    }

    // ---- epilogue: O^T -> O via per-wave LDS, then coalesced bf16 stores ----
    #pragma unroll
    for (int m = 0; m < 2; ++m) {
        const float inv = 1.0f / l_i[m];
        #pragma unroll
        for (int df = 0; df < 4; ++df) {
            uint2 pr;
            pr.x = pack2bf(acc_ot[m][df][0] * inv, acc_ot[m][df][1] * inv);
            pr.y = pack2bf(acc_ot[m][df][2] * inv, acc_ot[m][df][3] * inv);
            *(uint2*)&pw[lr * 36 + df * 8 + hi4 * 2] = pr;
        }
        #pragma unroll
        for (int ks2 = 0; ks2 < 2; ++ks2) {
            const u32x4 ov = *(const u32x4*)&pw[lr * 36 + ks2 * 16 + hi4 * 4];
            *(u32x4*)&Og[hb + (size_t)(qwave + m * 16 + lr) * DK + ks2 * 32 + hi4 * 8] = ov;
        }
    }
}

// ============ Kernel 3: output projection (bf16 MFMA) ============
__global__ __launch_bounds__(256)
void out_proj_kernel(const unsigned short* __restrict__ Ob,   // [b][h][t][d] bf16
                     const unsigned short* __restrict__ WoT,  // [1024][1024] bf16 (Wo^T)
                     float* __restrict__ out)
{
    __shared__ u32x4 Asv[512];
    __shared__ u32x4 Bsv[512];
    const int tid  = threadIdx.x;
    const int col0 = blockIdx.x * 128;
    const int row0 = blockIdx.y * 128;
    const int l = tid & 63, w = tid >> 6;
    const int wr = w >> 1, wc = w & 1;
    const int lr = l & 15, hi4 = l >> 4;
    const int bb = row0 >> 11, trow0 = row0 & 2047;

    f32x4 acc[4][4];
    #pragma unroll
    for (int m = 0; m < 4; ++m)
        #pragma unroll
        for (int n = 0; n < 4; ++n)
            acc[m][n] = (f32x4){0.f, 0.f, 0.f, 0.f};

    for (int k0 = 0; k0 < DM; k0 += 32) {
        __syncthreads();
        #pragma unroll
        for (int pass = 0; pass < 2; ++pass) {
            const int c = pass * 256 + tid;
            const int row = c >> 2, kb = c & 3;
            const int k = k0 + kb * 8;
            const int hh = k >> 6, dd = k & 63;
            Asv[kb * 128 + row] =
                *(const u32x4*)&Ob[((size_t)(bb * H_ + hh) * T_ + trow0 + row) * DK + dd];
            Bsv[kb * 128 + row] =
                *(const u32x4*)&WoT[(size_t)(col0 + row) * DM + k0 + kb * 8];
        }
        __syncthreads();
        u32x4 a[4], b[4];
        #pragma unroll
        for (int m = 0; m < 4; ++m) a[m] = Asv[hi4 * 128 + wr * 64 + m * 16 + lr];
        #pragma unroll
        for (int n = 0; n < 4; ++n) b[n] = Bsv[hi4 * 128 + wc * 64 + n * 16 + lr];
        #pragma unroll
        for (int m = 0; m < 4; ++m)
            #pragma unroll
            for (int n = 0; n < 4; ++n)
                acc[m][n] = __builtin_amdgcn_mfma_f32_16x16x32_bf16(
                    __builtin_bit_cast(bf16x8, a[m]),
                    __builtin_bit_cast(bf16x8, b[n]),
                    acc[m][n], 0, 0, 0);
    }

    #pragma unroll
    for (int n = 0; n < 4; ++n) {
        const int gc = col0 + wc * 64 + n * 16 + lr;
        #pragma unroll
        for (int m = 0; m < 4; ++m)
            #pragma unroll
            for (int r = 0; r < 4; ++r)
                out[(size_t)(row0 + wr * 64 + m * 16 + hi4 * 4 + r) * DM + gc] = acc[m][n][r];
    }
}

extern "C" void kernel_launch(void* const* d_in, const int* in_sizes, int n_in,
                              void* d_out, int out_size, void* d_ws, size_t ws_size,
                              hipStream_t stream)
{
    const float* x    = (const float*)d_in[0];
    const float* Wqkv = (const float*)d_in[1];
    const float* Wo   = (const float*)d_in[2];
    const int*   pos  = (const int*)d_in[3];
    float* out = (float*)d_out;

    unsigned short* ws    = (unsigned short*)d_ws;
    unsigned short* xb    = ws;                      // 8388608
    unsigned short* WqkvT = xb    + 8388608;         // 3145728
    unsigned short* WoT   = WqkvT + 3145728;         // 1048576
    unsigned short* Qb    = WoT   + 1048576;         // 8388608
    unsigned short* Kb    = Qb    + 8388608;         // 8388608
    unsigned short* Vtb   = Kb    + 8388608;         // 8388608  ([b][h][d][t])
    unsigned short* Ob    = Vtb   + 8388608;         // 8388608

    convert_copy<<<dim3(4096), 256, 0, stream>>>(x, xb, 1048576);
    convert_T<<<dim3(96, 32), 256, 0, stream>>>(Wqkv, WqkvT, 1024, 3072);
    convert_T<<<dim3(32, 32), 256, 0, stream>>>(Wo, WoT, 1024, 1024);
    qkv_rope_kernel<<<dim3(24, 64), 256, 0, stream>>>(xb, WqkvT, pos, Qb, Kb, Vtb);
    flash_attn_kernel<<<dim3(1024), 256, 0, stream>>>(Qb, Kb, Vtb, Ob);
    out_proj_kernel<<<dim3(8, 64), 256, 0, stream>>>(Ob, WoT, out);
}

// Round 9
// 280.107 us; speedup vs baseline: 1.4313x; 1.1232x over previous
//
#include <hip/hip_runtime.h>
#include <math.h>

#define B_  4
#define T_  2048
#define DM  1024
#define H_  16
#define DK  64
#define N3  3072

typedef __attribute__((ext_vector_type(8))) __bf16 bf16x8;
typedef __attribute__((ext_vector_type(4))) float f32x4;
typedef __attribute__((ext_vector_type(4))) unsigned int u32x4;

static __device__ __forceinline__ unsigned int f2bf(float f) {
    union { float f; unsigned int u; } v; v.f = f;
    return (v.u + 0x7fffu + ((v.u >> 16) & 1u)) >> 16;   // RNE
}
static __device__ __forceinline__ unsigned int pack2bf(float a, float b) {
    return f2bf(a) | (f2bf(b) << 16);
}
// async global->LDS, 16B per lane; LDS dest = first-lane base + lane*16 (linear)
static __device__ __forceinline__ void gload_lds16(const void* g, void* l) {
    __builtin_amdgcn_global_load_lds(
        (const __attribute__((address_space(1))) unsigned int*)g,
        (__attribute__((address_space(3))) unsigned int*)l, 16, 0, 0);
}

// ---------------- prep: fp32 -> bf16 straight copy (x) ----------------
__global__ __launch_bounds__(256)
void convert_copy(const float* __restrict__ src, unsigned short* __restrict__ dst, int n8)
{
    const int i = blockIdx.x * 256 + threadIdx.x;
    if (i >= n8) return;
    const float4 f0 = ((const float4*)src)[i * 2];
    const float4 f1 = ((const float4*)src)[i * 2 + 1];
    u32x4 wv;
    wv.x = pack2bf(f0.x, f0.y); wv.y = pack2bf(f0.z, f0.w);
    wv.z = pack2bf(f1.x, f1.y); wv.w = pack2bf(f1.z, f1.w);
    ((u32x4*)dst)[i] = wv;
}

// ---------------- prep: fp32 [K][N] -> bf16 transposed [N][K] ----------------
__global__ __launch_bounds__(256)
void convert_T(const float* __restrict__ src, unsigned short* __restrict__ dst, int K, int N)
{
    __shared__ float tile[32][33];
    const int n0 = blockIdx.x * 32, k0 = blockIdx.y * 32;
    const int tid = threadIdx.x;
    #pragma unroll
    for (int p = 0; p < 4; ++p) {
        const int idx = p * 256 + tid;
        const int r = idx >> 5, c = idx & 31;
        tile[r][c] = src[(size_t)(k0 + r) * N + n0 + c];
    }
    __syncthreads();
    #pragma unroll
    for (int p = 0; p < 4; ++p) {
        const int idx = p * 256 + tid;
        const int r = idx >> 5, c = idx & 31;
        dst[(size_t)(n0 + r) * K + k0 + c] = (unsigned short)f2bf(tile[c][r]);
    }
}

// ============ Kernel 1: QKV GEMM (bf16 MFMA) + RoPE ============
// Q pre-scaled by 1/8. Writes Q,K as [b][h][t][d], V as Vt [b][h][d][t].
// Staging via global_load_lds width=16 (linear LDS dest, no ds_write conflicts).
__global__ __launch_bounds__(256)
void qkv_rope_kernel(const unsigned short* __restrict__ xb,     // [8192][1024] bf16
                     const unsigned short* __restrict__ WT,     // [3072][1024] bf16 (Wqkv^T)
                     const int* __restrict__ pos,
                     unsigned short* __restrict__ Qb,
                     unsigned short* __restrict__ Kb,
                     unsigned short* __restrict__ Vtb)
{
    __shared__ u32x4 Asv[512];   // [kb 4][row 128], chunk idx = kb*128+row
    __shared__ u32x4 Bsv[512];
    const int tid  = threadIdx.x;
    const int col0 = blockIdx.x * 128;   // 24 tiles over N=3072
    const int row0 = blockIdx.y * 128;   // 64 tiles over M=8192
    const int l = tid & 63, w = tid >> 6;
    const int wr = w >> 1, wc = w & 1;
    const int lr = l & 15, hi4 = l >> 4;

    f32x4 acc[4][4];
    #pragma unroll
    for (int m = 0; m < 4; ++m)
        #pragma unroll
        for (int n = 0; n < 4; ++n)
            acc[m][n] = (f32x4){0.f, 0.f, 0.f, 0.f};

    for (int k0 = 0; k0 < DM; k0 += 32) {
        __syncthreads();
        #pragma unroll
        for (int pass = 0; pass < 2; ++pass) {
            const int i = pass * 256 + tid;        // chunk idx == i (linear per wave)
            const int row = i & 127, kb = i >> 7;  // kb in {0,1} pass0, {2,3} pass1
            gload_lds16(&xb[(size_t)(row0 + row) * DM + k0 + kb * 8], &Asv[i]);
            gload_lds16(&WT[(size_t)(col0 + row) * DM + k0 + kb * 8], &Bsv[i]);
        }
        __syncthreads();
        u32x4 a[4], b[4];
        #pragma unroll
        for (int m = 0; m < 4; ++m) a[m] = Asv[hi4 * 128 + wr * 64 + m * 16 + lr];
        #pragma unroll
        for (int n = 0; n < 4; ++n) b[n] = Bsv[hi4 * 128 + wc * 64 + n * 16 + lr];
        #pragma unroll
        for (int m = 0; m < 4; ++m)
            #pragma unroll
            for (int n = 0; n < 4; ++n)
                acc[m][n] = __builtin_amdgcn_mfma_f32_16x16x32_bf16(
                    __builtin_bit_cast(bf16x8, a[m]),
                    __builtin_bit_cast(bf16x8, b[n]),
                    acc[m][n], 0, 0, 0);
    }

    const int which = col0 >> 10;                      // 0=q 1=k 2=v (tile never crosses)
    const int h     = ((col0 & 1023) >> 6) + wc;
    const int bb    = row0 >> 11;
    const int t0w   = (row0 & 2047) + wr * 64;

    if (which == 2) {
        // V: lane holds t-run of 4 for fixed d -> free transpose, write Vt[d][t]
        #pragma unroll
        for (int n = 0; n < 4; ++n) {
            const int d = n * 16 + lr;
            #pragma unroll
            for (int m = 0; m < 4; ++m) {
                uint2 val;
                val.x = pack2bf(acc[m][n][0], acc[m][n][1]);
                val.y = pack2bf(acc[m][n][2], acc[m][n][3]);
                *(uint2*)&Vtb[((size_t)(bb * H_ + h) * DK + d) * T_ + t0w + m * 16 + hi4 * 4] = val;
            }
        }
    } else {
        unsigned short* dst = (which == 0) ? Qb : Kb;
        const float postscale = (which == 0) ? 0.125f : 1.0f;   // fold 1/sqrt(dk) into Q
        #pragma unroll
        for (int n = 0; n < 4; ++n) {
            const int d = n * 16 + lr;
            const float ifr = __powf(10000.0f, -(float)(d & ~1) * (1.0f / 64.0f));
            #pragma unroll
            for (int m = 0; m < 4; ++m)
                #pragma unroll
                for (int r = 0; r < 4; ++r) {
                    const int t = t0w + m * 16 + hi4 * 4 + r;
                    const float v = acc[m][n][r];
                    const float partner = __shfl_xor(v, 1, 64);   // pair (d^1)
                    float s, c;
                    __sincosf((float)pos[t] * ifr, &s, &c);
                    const float rv = ((d & 1) ? (partner * s + v * c) : (v * c - partner * s)) * postscale;
                    dst[((size_t)(bb * H_ + h) * T_ + t) * DK + d] = (unsigned short)f2bf(rv);
                }
        }
    }
}

// ============ Kernel 2: causal flash attention, swapped-operand bf16 MFMA ============
// Round-6 structure (single-buffered staging) + XCD-aware 1D block swizzle:
// lin = qt*64 + (b*16+h)  =>  lin % 8 == headgroup % 8, so all 16 q-blocks of one
// head land on ONE XCD and its L2 holds that head's K/V (8 groups x 512KB = 4MB).
__global__ __launch_bounds__(256)
void flash_attn_kernel(const unsigned short* __restrict__ Qg,
                       const unsigned short* __restrict__ Kg,
                       const unsigned short* __restrict__ Vtg,
                       unsigned short* __restrict__ Og)
{
    __shared__ u32x4 K4[512];              // [kv 64][chunk 8], chunk ^= kv&7
    __shared__ u32x4 Vt4[512];             // [d 64][chunk 8],  chunk ^= d&7
    __shared__ unsigned int Pex[4][16 * 36];  // per-wave [q 16][word], stride 36

    const int tid = threadIdx.x;
    const int l = tid & 63, w = tid >> 6;
    const int lr = l & 15, hi4 = l >> 4;
    const int lin = blockIdx.x;            // 1024 blocks
    const int qt  = 15 - (lin >> 6);       // longest q-tiles first
    const int g   = lin & 63;              // headgroup: same g -> same XCD (g%8)
    const int h   = g & 15, b = g >> 4;
    const int q0 = qt * 128;
    const size_t hb = (size_t)(b * H_ + h) * T_ * DK;
    unsigned int* pw = &Pex[w][0];

    // Q fragments (B-operand: col=lr -> q-row, k=d=ks*32+hi4*8+j)
    u32x4 qf[2][2];
    #pragma unroll
    for (int m = 0; m < 2; ++m)
        #pragma unroll
        for (int ks = 0; ks < 2; ++ks)
            qf[m][ks] = *(const u32x4*)&Qg[hb + (size_t)(q0 + w * 32 + m * 16 + lr) * DK
                                           + ks * 32 + hi4 * 8];

    f32x4 acc_ot[2][4];                    // [m][df]: O^T frag, col=q(lr), row=d
    float m_i[2], l_i[2];
    #pragma unroll
    for (int m = 0; m < 2; ++m) {
        m_i[m] = -INFINITY; l_i[m] = 0.f;
        #pragma unroll
        for (int df = 0; df < 4; ++df) acc_ot[m][df] = (f32x4){0.f, 0.f, 0.f, 0.f};
    }

    const int qwave = q0 + w * 32;
    const int nkt = (q0 >> 6) + 2;
    for (int kt = 0; kt < nkt; ++kt) {
        const int kv0 = kt * 64;
        __syncthreads();
        #pragma unroll
        for (int pass = 0; pass < 2; ++pass) {
            const int c = pass * 256 + tid;
            const int row = c >> 3, cc = c & 7;
            K4 [row * 8 + (cc ^ (row & 7))] = *(const u32x4*)&Kg [hb + (size_t)(kv0 + row) * DK + cc * 8];
            Vt4[row * 8 + (cc ^ (row & 7))] = *(const u32x4*)&Vtg[hb + (size_t)row * T_ + kv0 + cc * 8];
        }
        __syncthreads();
        if (kv0 > qwave + 31) continue;    // wave-uniform: fully masked

        // ---- S^T = mfma(K, Q): D col=q(lr), row=kv(nf*16+hi4*4+r) ----
        f32x4 st[2][4];
        #pragma unroll
        for (int m = 0; m < 2; ++m)
            #pragma unroll
            for (int nf = 0; nf < 4; ++nf)
                st[m][nf] = (f32x4){0.f, 0.f, 0.f, 0.f};
        #pragma unroll
        for (int ks = 0; ks < 2; ++ks) {
            u32x4 kb4[4];
            #pragma unroll
            for (int nf = 0; nf < 4; ++nf) {
                const int row = nf * 16 + lr;
                kb4[nf] = K4[row * 8 + ((ks * 4 + hi4) ^ (row & 7))];
            }
            #pragma unroll
            for (int m = 0; m < 2; ++m)
                #pragma unroll
                for (int nf = 0; nf < 4; ++nf)
                    st[m][nf] = __builtin_amdgcn_mfma_f32_16x16x32_bf16(
                        __builtin_bit_cast(bf16x8, kb4[nf]),
                        __builtin_bit_cast(bf16x8, qf[m][ks]), st[m][nf], 0, 0, 0);
        }

        const bool needmask = (kv0 + 63 > qwave);
        u32x4 pfrag[2][2];
        #pragma unroll
        for (int m = 0; m < 2; ++m) {
            const int qg = qwave + m * 16 + lr;
            float sv[4][4];
            #pragma unroll
            for (int nf = 0; nf < 4; ++nf)
                #pragma unroll
                for (int r = 0; r < 4; ++r) {
                    float xv = st[m][nf][r];
                    if (needmask && (kv0 + nf * 16 + hi4 * 4 + r) > qg) xv = -INFINITY;
                    sv[nf][r] = xv;
                }
            // row max: 15 local + 2 shuffles (over hi4 groups)
            float mx = sv[0][0];
            #pragma unroll
            for (int nf = 0; nf < 4; ++nf)
                #pragma unroll
                for (int r = 0; r < 4; ++r) mx = fmaxf(mx, sv[nf][r]);
            mx = fmaxf(mx, __shfl_xor(mx, 16, 64));
            mx = fmaxf(mx, __shfl_xor(mx, 32, 64));
            const float mnew = fmaxf(m_i[m], mx);
            const float alpha = __expf(m_i[m] - mnew);
            m_i[m] = mnew;
            float p[4][4], rs = 0.f;
            #pragma unroll
            for (int nf = 0; nf < 4; ++nf)
                #pragma unroll
                for (int r = 0; r < 4; ++r) {
                    p[nf][r] = __expf(sv[nf][r] - mnew);
                    rs += p[nf][r];
                }
            rs += __shfl_xor(rs, 16, 64);
            rs += __shfl_xor(rs, 32, 64);
            l_i[m] = l_i[m] * alpha + rs;
            #pragma unroll
            for (int df = 0; df < 4; ++df) acc_ot[m][df] *= alpha;
            // pack P row -> per-wave LDS exchange [q=lr][word=kv/2], stride 36
            #pragma unroll
            for (int nf = 0; nf < 4; ++nf) {
                uint2 pr;
                pr.x = pack2bf(p[nf][0], p[nf][1]);
                pr.y = pack2bf(p[nf][2], p[nf][3]);
                *(uint2*)&pw[lr * 36 + nf * 8 + hi4 * 2] = pr;
            }
            // read back as B-frag: col=q(lr), k = kv = ks*32 + hi4*8 + j
            #pragma unroll
            for (int ks = 0; ks < 2; ++ks)
                pfrag[m][ks] = *(const u32x4*)&pw[lr * 36 + ks * 16 + hi4 * 4];
        }

        // ---- O^T += mfma(Vt, P): col=q(lr), row=d ----
        #pragma unroll
        for (int ks = 0; ks < 2; ++ks) {
            u32x4 vb[4];
            #pragma unroll
            for (int df = 0; df < 4; ++df) {
                const int d = df * 16 + lr;
                vb[df] = Vt4[d * 8 + ((ks * 4 + hi4) ^ (d & 7))];
            }
            #pragma unroll
            for (int m = 0; m < 2; ++m)
                #pragma unroll
                for (int df = 0; df < 4; ++df)
                    acc_ot[m][df] = __builtin_amdgcn_mfma_f32_16x16x32_bf16(
                        __builtin_bit_cast(bf16x8, vb[df]),
                        __builtin_bit_cast(bf16x8, pfrag[m][ks]), acc_ot[m][df], 0, 0, 0);
        }
    }

    // ---- epilogue: O^T -> O via per-wave LDS, then coalesced bf16 stores ----
    #pragma unroll
    for (int m = 0; m < 2; ++m) {
        const float inv = 1.0f / l_i[m];
        #pragma unroll
        for (int df = 0; df < 4; ++df) {
            uint2 pr;
            pr.x = pack2bf(acc_ot[m][df][0] * inv, acc_ot[m][df][1] * inv);
            pr.y = pack2bf(acc_ot[m][df][2] * inv, acc_ot[m][df][3] * inv);
            *(uint2*)&pw[lr * 36 + df * 8 + hi4 * 2] = pr;
        }
        #pragma unroll
        for (int ks2 = 0; ks2 < 2; ++ks2) {
            const u32x4 ov = *(const u32x4*)&pw[lr * 36 + ks2 * 16 + hi4 * 4];
            *(u32x4*)&Og[hb + (size_t)(qwave + m * 16 + lr) * DK + ks2 * 32 + hi4 * 8] = ov;
        }
    }
}

// ============ Kernel 3: output projection (bf16 MFMA) ============
__global__ __launch_bounds__(256)
void out_proj_kernel(const unsigned short* __restrict__ Ob,   // [b][h][t][d] bf16
                     const unsigned short* __restrict__ WoT,  // [1024][1024] bf16 (Wo^T)
                     float* __restrict__ out)
{
    __shared__ u32x4 Asv[512];
    __shared__ u32x4 Bsv[512];
    const int tid  = threadIdx.x;
    const int col0 = blockIdx.x * 128;
    const int row0 = blockIdx.y * 128;
    const int l = tid & 63, w = tid >> 6;
    const int wr = w >> 1, wc = w & 1;
    const int lr = l & 15, hi4 = l >> 4;
    const int bb = row0 >> 11, trow0 = row0 & 2047;

    f32x4 acc[4][4];
    #pragma unroll
    for (int m = 0; m < 4; ++m)
        #pragma unroll
        for (int n = 0; n < 4; ++n)
            acc[m][n] = (f32x4){0.f, 0.f, 0.f, 0.f};

    for (int k0 = 0; k0 < DM; k0 += 32) {
        __syncthreads();
        #pragma unroll
        for (int pass = 0; pass < 2; ++pass) {
            const int i = pass * 256 + tid;
            const int row = i & 127, kb = i >> 7;
            const int k = k0 + kb * 8;
            const int hh = k >> 6, dd = k & 63;
            gload_lds16(&Ob[((size_t)(bb * H_ + hh) * T_ + trow0 + row) * DK + dd], &Asv[i]);
            gload_lds16(&WoT[(size_t)(col0 + row) * DM + k0 + kb * 8], &Bsv[i]);
        }
        __syncthreads();
        u32x4 a[4], b[4];
        #pragma unroll
        for (int m = 0; m < 4; ++m) a[m] = Asv[hi4 * 128 + wr * 64 + m * 16 + lr];
        #pragma unroll
        for (int n = 0; n < 4; ++n) b[n] = Bsv[hi4 * 128 + wc * 64 + n * 16 + lr];
        #pragma unroll
        for (int m = 0; m < 4; ++m)
            #pragma unroll
            for (int n = 0; n < 4; ++n)
                acc[m][n] = __builtin_amdgcn_mfma_f32_16x16x32_bf16(
                    __builtin_bit_cast(bf16x8, a[m]),
                    __builtin_bit_cast(bf16x8, b[n]),
                    acc[m][n], 0, 0, 0);
    }

    #pragma unroll
    for (int n = 0; n < 4; ++n) {
        const int gc = col0 + wc * 64 + n * 16 + lr;
        #pragma unroll
        for (int m = 0; m < 4; ++m)
            #pragma unroll
            for (int r = 0; r < 4; ++r)
                out[(size_t)(row0 + wr * 64 + m * 16 + hi4 * 4 + r) * DM + gc] = acc[m][n][r];
    }
}

extern "C" void kernel_launch(void* const* d_in, const int* in_sizes, int n_in,
                              void* d_out, int out_size, void* d_ws, size_t ws_size,
                              hipStream_t stream)
{
    const float* x    = (const float*)d_in[0];
    const float* Wqkv = (const float*)d_in[1];
    const float* Wo   = (const float*)d_in[2];
    const int*   pos  = (const int*)d_in[3];
    float* out = (float*)d_out;

    unsigned short* ws    = (unsigned short*)d_ws;
    unsigned short* xb    = ws;                      // 8388608
    unsigned short* WqkvT = xb    + 8388608;         // 3145728
    unsigned short* WoT   = WqkvT + 3145728;         // 1048576
    unsigned short* Qb    = WoT   + 1048576;         // 8388608
    unsigned short* Kb    = Qb    + 8388608;         // 8388608
    unsigned short* Vtb   = Kb    + 8388608;         // 8388608  ([b][h][d][t])
    unsigned short* Ob    = Vtb   + 8388608;         // 8388608

    convert_copy<<<dim3(4096), 256, 0, stream>>>(x, xb, 1048576);
    convert_T<<<dim3(96, 32), 256, 0, stream>>>(Wqkv, WqkvT, 1024, 3072);
    convert_T<<<dim3(32, 32), 256, 0, stream>>>(Wo, WoT, 1024, 1024);
    qkv_rope_kernel<<<dim3(24, 64), 256, 0, stream>>>(xb, WqkvT, pos, Qb, Kb, Vtb);
    flash_attn_kernel<<<dim3(1024), 256, 0, stream>>>(Qb, Kb, Vtb, Ob);
    out_proj_kernel<<<dim3(8, 64), 256, 0, stream>>>(Ob, WoT, out);
}